// Round 1
// 5741.189 us; speedup vs baseline: 1.2234x; 1.2234x over previous
//
#include <hip/hip_runtime.h>
#include <stdint.h>

#define TT 512
#define BB 64
#define II 512
#define HH 512
#define GG 2048   // 4H
#define KK 1024   // I + H

typedef short short8 __attribute__((ext_vector_type(8)));
typedef float floatx4 __attribute__((ext_vector_type(4)));

// workspace layout
static constexpr size_t WX_BYTES   = (size_t)2 * GG * II * 2;       // 4 MB bf16 [dir][2048][512]  x-part weights
static constexpr size_t WH_BYTES   = (size_t)2 * 32 * 32768 * 2;    // 4 MB bf16 [dir][blk][32768] h-part frag images
static constexpr size_t XB_BYTES   = (size_t)TT * BB * II * 2;      // 32 MB bf16 [T][B][I]
static constexpr size_t FLAG_INTS  = (size_t)2 * TT * 32 * 32;     // 4 MB: flags[dir][t][blk] 128B padded; +wid*8 sub-slot
static constexpr size_t FLAG_BYTES = FLAG_INTS * 4;
static constexpr size_t HX_BYTES   = (size_t)2 * TT * BB * HH * 2;  // 64 MB bf16 [dir][t][B][H] h-exchange

__device__ __forceinline__ unsigned short f2bf(float f) {
  unsigned int u = __float_as_uint(f);
  unsigned int r = (u + 0x7fffu + ((u >> 16) & 1u)) >> 16;   // round-to-nearest-even
  return (unsigned short)r;
}

// ---- prep: weights -> wx (x-part, [dir][n][k<512]) + wh (h-part frag image
//      [g][kc][quad][j][8]); zero flags
__global__ void prep_kernel(const float* __restrict__ Wih_f, const float* __restrict__ Whh_f,
                            const float* __restrict__ Wih_b, const float* __restrict__ Whh_b,
                            unsigned short* __restrict__ wx,
                            unsigned short* __restrict__ wh,
                            int* __restrict__ flags)
{
  size_t tid0 = (size_t)blockIdx.x * blockDim.x + threadIdx.x;
  size_t stride = (size_t)gridDim.x * blockDim.x;

  const size_t WC = (size_t)2 * GG * KK;   // 2^22
  for (size_t idx = tid0; idx < WC; idx += stride) {
    int dir = (int)(idx >> 21);
    int rem = (int)(idx & ((1u << 21) - 1));
    int n = rem >> 10;        // 0..2047
    int k = rem & 1023;       // 0..1023
    if (k < II) {
      const float* Wih = dir ? Wih_b : Wih_f;
      wx[(size_t)dir * GG * II + (size_t)n * II + k] = f2bf(Wih[(size_t)n * II + k]);
    } else {
      const float* Whh = dir ? Whh_b : Whh_f;
      int kk = k - II;            // 0..511
      int kc = kk >> 5;           // 0..15
      int r  = kk & 31;
      int quad = r >> 3;          // 0..3
      int e  = r & 7;             // 0..7
      int g   = n >> 9;           // 0..3
      int blk = (n >> 4) & 31;    // 0..31
      int j   = n & 15;           // 0..15
      size_t lidx = ((size_t)((g * 16 + kc) * 4 + quad) * 16 + j) * 8 + e;
      wh[((size_t)dir * 32 + blk) * 32768 + lidx] = f2bf(Whh[(size_t)n * HH + kk]);
    }
  }

  for (size_t idx = tid0; idx < FLAG_INTS; idx += stride) flags[idx] = 0;
}

// ---- x -> bf16
__global__ void xconv_kernel(const float* __restrict__ x, unsigned short* __restrict__ xb) {
  size_t i = (size_t)blockIdx.x * blockDim.x + threadIdx.x;
  size_t stride = (size_t)gridDim.x * blockDim.x;
  const size_t n4 = (size_t)TT * BB * II / 4;
  const float4* xp = (const float4*)x;
  ushort4* op = (ushort4*)xb;
  for (; i < n4; i += stride) {
    float4 v = xp[i];
    ushort4 o;
    o.x = f2bf(v.x); o.y = f2bf(v.y); o.z = f2bf(v.z); o.w = f2bf(v.w);
    op[i] = o;
  }
}

// ---- persistent bidirectional LSTM
// grid = 64 blocks: dir = bid>>5, j-slice = (bid&31)*16. 4 waves/block (wave = m-tile).
//
// Round-5 changes vs round 4 (13.4 us/step; MfmaUtil 1.6% => pure handoff latency):
//  * LL-style handoff: h published as bf16 via relaxed AGENT-scope atomic stores
//    (write-through to coherence point, nothing left dirty in L2), then
//    s_waitcnt vmcnt(0), then RELAXED flag store. No release-RMW => no per-step
//    buffer_wbl2 full-L2 flush on the critical path.
//  * poll with relaxed AGENT atomic LOADS (no RMW serialization at the flag
//    lines); escalates to the proven fetch_add(0) after 32 spins as insurance.
//  * per-wave flags ([t][blk]*32 + wid*8 int): wave w only consumes rows made by
//    wave w of other blocks => 4 independent pipelines, ZERO __syncthreads in
//    the t-loop.
//  * h-part weights live in VGPRs (64 x bf16x8 = 256 regs/lane, budget 512 at
//    __launch_bounds__(256,1)): removes ~1024 cyc/step of LDS pipe time + the
//    staging barrier. LDS no longer used at all.
//  * fp32 out stores (cached) moved AFTER the flag publish — off critical path.
// Fallbacks: HXB=false exchanges fp32 through `out` (write-through) with the
// same sync protocol; XBF16=false reads x as fp32.
template<bool XBF16, bool HXB>
__global__ __launch_bounds__(256, 1) void lstm_kernel(
    const float* __restrict__ x_f32,
    const unsigned short* __restrict__ xb,
    const unsigned short* __restrict__ wx,
    const unsigned short* __restrict__ wh,
    int* __restrict__ flags,
    const float* __restrict__ h0,
    const float* __restrict__ c0,
    const float* __restrict__ b_f,
    const float* __restrict__ b_b,
    float* __restrict__ out,
    unsigned short* __restrict__ hx)
{
  const int bid  = blockIdx.x;
  const int dir  = bid >> 5;
  const int blk  = bid & 31;
  const int j0   = blk << 4;
  const int tid  = threadIdx.x;
  const int lane = tid & 63;
  const int l15  = lane & 15;
  const int quad = lane >> 4;
  const int wid  = tid >> 6;
  const int m0   = wid << 4;

  // ---- h-part weights resident in VGPRs: frag (g,kc) at wb[g*16+kc] ----
  short8 wb[64];
  {
    const unsigned short* wsrc = wh + ((size_t)dir * 32 + blk) * 32768
                                    + (size_t)(quad * 16 + l15) * 8;
#pragma unroll
    for (int f = 0; f < 64; ++f)
      wb[f] = *(const short8*)(wsrc + (size_t)f * 512);
  }

  const float* bias = dir ? b_b : b_f;
  float bs[4];
#pragma unroll
  for (int g = 0; g < 4; ++g) bs[g] = bias[g * HH + j0 + l15];

  // c state in registers: C/D layout -> row = m0 + quad*4 + r, col = j0 + l15
  float cst[4];
#pragma unroll
  for (int r = 0; r < 4; ++r)
    cst[r] = c0[(size_t)dir * BB * HH + (size_t)(m0 + quad * 4 + r) * HH + j0 + l15];

  // x-part B row pointers (global, [n][k<512])
  const unsigned short* wxrow[4];
#pragma unroll
  for (int g = 0; g < 4; ++g)
    wxrow[g] = wx + (size_t)dir * GG * II + (size_t)(g * HH + j0 + l15) * II + quad * 8;

  int* fl_dir = flags + (size_t)dir * TT * 32 * 32;

  for (int t = 0; t < TT; ++t) {
    const int tt2 = dir ? (TT - 1 - t) : t;

    floatx4 acc[4];
#pragma unroll
    for (int g = 0; g < 4; ++g) acc[g] = (floatx4){0.f, 0.f, 0.f, 0.f};

    // ---- x contribution (k = 0..511): independent of h, overlaps the wait ----
    if (XBF16) {
      const unsigned short* arow = xb + (size_t)tt2 * BB * II + (size_t)(m0 + l15) * II + quad * 8;
#pragma unroll
      for (int kc = 0; kc < 16; ++kc) {
        short8 a = *(const short8*)(arow + kc * 32);
#pragma unroll
        for (int g = 0; g < 4; ++g) {
          short8 b = *(const short8*)(wxrow[g] + kc * 32);
          acc[g] = __builtin_amdgcn_mfma_f32_16x16x32_bf16(a, b, acc[g], 0, 0, 0);
        }
      }
    } else {
      const float* arow = x_f32 + (size_t)tt2 * BB * II + (size_t)(m0 + l15) * II + quad * 8;
#pragma unroll
      for (int kc = 0; kc < 16; ++kc) {
        float4 v0 = *(const float4*)(arow + kc * 32);
        float4 v1 = *(const float4*)(arow + kc * 32 + 4);
        short8 a;
        a[0] = (short)f2bf(v0.x); a[1] = (short)f2bf(v0.y);
        a[2] = (short)f2bf(v0.z); a[3] = (short)f2bf(v0.w);
        a[4] = (short)f2bf(v1.x); a[5] = (short)f2bf(v1.y);
        a[6] = (short)f2bf(v1.z); a[7] = (short)f2bf(v1.w);
#pragma unroll
        for (int g = 0; g < 4; ++g) {
          short8 b = *(const short8*)(wxrow[g] + kc * 32);
          acc[g] = __builtin_amdgcn_mfma_f32_16x16x32_bf16(a, b, acc[g], 0, 0, 0);
        }
      }
    }

    // ---- wait for h_{t-1}: per-wave, relaxed atomic LOAD poll, no barrier ----
    if (t > 0) {
      int* fl = fl_dir + (((size_t)(t - 1) << 5) + (lane & 31)) * 32 + wid * 8;
      int v = 1, spin = 0;
      while (true) {
        if (lane < 32)
          v = (spin < 32)
            ? __hip_atomic_load(fl, __ATOMIC_RELAXED, __HIP_MEMORY_SCOPE_AGENT)
            : __hip_atomic_fetch_add(fl, 0, __ATOMIC_RELAXED, __HIP_MEMORY_SCOPE_AGENT);
        if (__ballot(v > 0) == ~0ull) break;
        ++spin;
        __builtin_amdgcn_s_sleep(1);
      }
      asm volatile("" ::: "memory");   // keep h loads below the wait
    }

    // ---- h contribution (k = 512..1023), B from VGPRs ----
    if (HXB && t > 0) {
      const unsigned short* hrow = hx + (((size_t)dir * TT + (t - 1)) * BB + (size_t)(m0 + l15)) * HH + quad * 8;
#pragma unroll
      for (int kc = 0; kc < 16; ++kc) {
        short8 a = *(const short8*)(hrow + kc * 32);
#pragma unroll
        for (int g = 0; g < 4; ++g)
          acc[g] = __builtin_amdgcn_mfma_f32_16x16x32_bf16(a, wb[g * 16 + kc], acc[g], 0, 0, 0);
      }
    } else {
      const float* hrow;
      if (t == 0) {
        hrow = h0 + (size_t)dir * BB * HH + (size_t)(m0 + l15) * HH + quad * 8;
      } else {
        const int tp = dir ? (TT - t) : (t - 1);
        hrow = out + (size_t)tp * BB * 2 * HH + (size_t)(m0 + l15) * 2 * HH + (size_t)dir * HH + quad * 8;
      }
#pragma unroll
      for (int kc = 0; kc < 16; ++kc) {
        float4 v0 = *(const float4*)(hrow + (size_t)kc * 32);
        float4 v1 = *(const float4*)(hrow + (size_t)kc * 32 + 4);
        short8 a;
        a[0] = (short)f2bf(v0.x); a[1] = (short)f2bf(v0.y);
        a[2] = (short)f2bf(v0.z); a[3] = (short)f2bf(v0.w);
        a[4] = (short)f2bf(v1.x); a[5] = (short)f2bf(v1.y);
        a[6] = (short)f2bf(v1.z); a[7] = (short)f2bf(v1.w);
#pragma unroll
        for (int g = 0; g < 4; ++g)
          acc[g] = __builtin_amdgcn_mfma_f32_16x16x32_bf16(a, wb[g * 16 + kc], acc[g], 0, 0, 0);
      }
    }

    // ---- gates + state update ----
    float hf[4];
#pragma unroll
    for (int r = 0; r < 4; ++r) {
      float gi = acc[0][r] + bs[0];
      float gf = acc[1][r] + bs[1];
      float gg = acc[2][r] + bs[2];
      float go = acc[3][r] + bs[3];
      float si = 1.f / (1.f + __expf(-gi));
      float sf = 1.f / (1.f + __expf(-gf));
      float tg = 2.f / (1.f + __expf(-2.f * gg)) - 1.f;
      float so = 1.f / (1.f + __expf(-go));
      float c  = sf * cst[r] + si * tg;
      cst[r] = c;
      float th = 2.f / (1.f + __expf(-2.f * c)) - 1.f;
      hf[r] = so * th;
    }

    if (HXB) {
      // publish bf16 h via write-through stores: pack adjacent columns (l15
      // pairs) into dwords, 2 x 4B relaxed AGENT atomic stores per lane
      unsigned int pk[4];
#pragma unroll
      for (int r = 0; r < 4; ++r) {
        unsigned int mine  = f2bf(hf[r]);
        unsigned int other = (unsigned int)(unsigned short)__shfl_xor((int)mine, 1);
        pk[r] = (l15 & 1) ? (other | (mine << 16)) : (mine | (other << 16));
      }
      unsigned short* hxt = hx + ((size_t)dir * TT + t) * BB * HH + (j0 + (l15 & ~1));
      const int rb = (l15 & 1) << 1;
#pragma unroll
      for (int rr = 0; rr < 2; ++rr) {
        int row = m0 + quad * 4 + rb + rr;
        __hip_atomic_store((unsigned int*)(hxt + (size_t)row * HH), pk[rb + rr],
                           __ATOMIC_RELAXED, __HIP_MEMORY_SCOPE_AGENT);
      }
      asm volatile("s_waitcnt vmcnt(0)" ::: "memory");   // h stores globally visible
      if (lane == 0)
        __hip_atomic_store(fl_dir + (((size_t)t << 5) + blk) * 32 + wid * 8, 1,
                           __ATOMIC_RELAXED, __HIP_MEMORY_SCOPE_AGENT);
      // fp32 output (cached, off critical path, flushed at kernel end)
      float* orow = out + (size_t)tt2 * BB * 2 * HH + (size_t)dir * HH + j0 + l15;
#pragma unroll
      for (int r = 0; r < 4; ++r)
        orow[(size_t)(m0 + quad * 4 + r) * 2 * HH] = hf[r];
    } else {
      // exchange fp32 h through `out` with write-through stores, same protocol
      float* orow = out + (size_t)tt2 * BB * 2 * HH + (size_t)dir * HH + j0 + l15;
#pragma unroll
      for (int r = 0; r < 4; ++r)
        __hip_atomic_store(&orow[(size_t)(m0 + quad * 4 + r) * 2 * HH], hf[r],
                           __ATOMIC_RELAXED, __HIP_MEMORY_SCOPE_AGENT);
      asm volatile("s_waitcnt vmcnt(0)" ::: "memory");
      if (lane == 0)
        __hip_atomic_store(fl_dir + (((size_t)t << 5) + blk) * 32 + wid * 8, 1,
                           __ATOMIC_RELAXED, __HIP_MEMORY_SCOPE_AGENT);
    }
  }
}

extern "C" void kernel_launch(void* const* d_in, const int* in_sizes, int n_in,
                              void* d_out, int out_size, void* d_ws, size_t ws_size,
                              hipStream_t stream)
{
  (void)in_sizes; (void)n_in; (void)out_size;
  const float* x     = (const float*)d_in[0];
  const float* h0    = (const float*)d_in[1];
  const float* c0    = (const float*)d_in[2];
  const float* Wih_f = (const float*)d_in[3];
  const float* Whh_f = (const float*)d_in[4];
  const float* b_f   = (const float*)d_in[5];
  const float* Wih_b = (const float*)d_in[6];
  const float* Whh_b = (const float*)d_in[7];
  const float* b_b   = (const float*)d_in[8];
  float* out = (float*)d_out;
  char* ws = (char*)d_ws;

  const bool xbf = ws_size >= (WX_BYTES + WH_BYTES + XB_BYTES + FLAG_BYTES);
  const bool hxb = ws_size >= (WX_BYTES + WH_BYTES + XB_BYTES + FLAG_BYTES + HX_BYTES);

  unsigned short* wx = (unsigned short*)ws;
  unsigned short* wh = (unsigned short*)(ws + WX_BYTES);
  unsigned short* xb = nullptr;
  unsigned short* hxp = nullptr;
  int* flags;
  if (xbf) {
    xb    = (unsigned short*)(ws + WX_BYTES + WH_BYTES);
    flags = (int*)(ws + WX_BYTES + WH_BYTES + XB_BYTES);
    if (hxb) hxp = (unsigned short*)(ws + WX_BYTES + WH_BYTES + XB_BYTES + FLAG_BYTES);
  } else {
    flags = (int*)(ws + WX_BYTES + WH_BYTES);
  }

  prep_kernel<<<512, 256, 0, stream>>>(Wih_f, Whh_f, Wih_b, Whh_b, wx, wh, flags);
  if (xbf) {
    xconv_kernel<<<2048, 256, 0, stream>>>(x, xb);
    if (hxb)
      lstm_kernel<true, true><<<64, 256, 0, stream>>>(x, xb, wx, wh, flags, h0, c0, b_f, b_b, out, hxp);
    else
      lstm_kernel<true, false><<<64, 256, 0, stream>>>(x, xb, wx, wh, flags, h0, c0, b_f, b_b, out, nullptr);
  } else {
    lstm_kernel<false, false><<<64, 256, 0, stream>>>(x, xb, wx, wh, flags, h0, c0, b_f, b_b, out, nullptr);
  }
}